// Round 1
// baseline (321.544 us; speedup 1.0000x reference)
//
#include <hip/hip_runtime.h>
#include <cstdint>

// ---------------------------------------------------------------------------
// SingleDeformConv on MI355X (gfx950)
// data (8,64,128,128) f32; w (64,64,3,3); b (64); w_off (18,64,3,3); b_off(18);
// w_mod (9,64,3,3); b_mod (9).  out = relu(deform_conv(...)) (8,64,128,128) f32
//
// Strategy: bf16 MFMA for both the 27-ch offset/mask conv (implicit GEMM) and
// the main einsum (per-tap gathered B-tiles). Data transposed to NHWC bf16 so
// one bilinear tap for all 64 channels is one coalesced 128B row load.
// ---------------------------------------------------------------------------

typedef __attribute__((ext_vector_type(8))) short short8;
typedef __attribute__((ext_vector_type(4))) float floatx4;

__device__ __forceinline__ unsigned short f2bf(float x) {
    unsigned int u = __float_as_uint(x);
    u += 0x7fffu + ((u >> 16) & 1u);           // round-to-nearest-even
    return (unsigned short)(u >> 16);
}
__device__ __forceinline__ float bf2f(unsigned short s) {
    return __uint_as_float(((unsigned int)s) << 16);
}

// Workspace layout (bytes)
#define OFF_DATAT 0u               // [8][16384][64] bf16  = 16777216 B
#define OFF_OFFP  16777216u        // [8][9][3][16384] f32 = 14155776 B (dy,dx,mask)
#define OFF_WM    30932992u        // [64][576] bf16       = 73728 B
#define OFF_W27   31006720u        // [32][576] bf16       = 36864 B
#define OFF_B27   31043584u        // [32] f32             = 128 B
// total 31043712 B

// ---------------------------------------------------------------------------
// Kernel 1: pack weights to bf16, K index = k*64 + c  (k = ky*3+kx)
// ---------------------------------------------------------------------------
__global__ void pack_weights_k(const float* __restrict__ w,
                               const float* __restrict__ w_off,
                               const float* __restrict__ w_mod,
                               const float* __restrict__ b_off,
                               const float* __restrict__ b_mod,
                               unsigned short* __restrict__ wpackM,
                               unsigned short* __restrict__ wpack27,
                               float* __restrict__ bias27) {
    int t = blockIdx.x * 256 + threadIdx.x;
    if (t < 64 * 576) {
        int o = t / 576, kk = t % 576;
        int k = kk >> 6, c = kk & 63;
        wpackM[t] = f2bf(w[(o * 64 + c) * 9 + k]);
        return;
    }
    t -= 64 * 576;
    if (t < 32 * 576) {
        int o = t / 576, kk = t % 576;
        int k = kk >> 6, c = kk & 63;
        float v = 0.f;
        if (o < 18)      v = w_off[(o * 64 + c) * 9 + k];
        else if (o < 27) v = w_mod[((o - 18) * 64 + c) * 9 + k];
        wpack27[t] = f2bf(v);
        if (kk == 0) bias27[o] = (o < 18) ? b_off[o] : (o < 27 ? b_mod[o - 18] : 0.f);
    }
}

// ---------------------------------------------------------------------------
// Kernel 2: NCHW f32 -> NHWC bf16 transpose.  64x64 tile per block.
// ---------------------------------------------------------------------------
__global__ __launch_bounds__(256) void transpose_k(const float* __restrict__ x,
                                                   unsigned short* __restrict__ xt) {
    __shared__ float tile[64][65];                 // +1 pad: conflict-free transpose
    int blk  = blockIdx.x;                         // 2048 = 8 b * 256 tiles
    int b    = blk >> 8;
    int pos0 = (blk & 255) << 6;
    int lane = threadIdx.x & 63;
    int g    = threadIdx.x >> 6;
    for (int c = g; c < 64; c += 4)
        tile[c][lane] = x[(((b << 6) + c) << 14) + pos0 + lane];   // coalesced 256B
    __syncthreads();
    for (int pr = g; pr < 64; pr += 4)
        xt[(size_t)(((b << 14) + pos0 + pr) << 6) + lane] = f2bf(tile[lane][pr]); // coalesced 128B
}

// ---------------------------------------------------------------------------
// Kernel 3: offset/mask conv (27 ch, padded to 32) — implicit GEMM, bf16 MFMA.
// Block: 256 thr (4 waves), 128 positions. Per tap k: stage im2col tile
// [128 pos][64 c] bf16 in LDS (pad to 72), then 2 K-chunks x 4 n-tiles MFMA.
// Wave (i_oc, j_pos): oc strip of 16, pos half of 64.
// Epilogue: dy/dx raw + bias; mask = 2*sigmoid; store f32 planes.
// ---------------------------------------------------------------------------
__global__ __launch_bounds__(256) void conv27_k(const unsigned short* __restrict__ xt,
                                                const unsigned short* __restrict__ wpack27,
                                                const float* __restrict__ bias27,
                                                float* __restrict__ offP) {
    __shared__ unsigned short tile[128][72];
    int blk  = blockIdx.x;                          // 1024 = 8 b * 128
    int b    = blk >> 7;
    int pos0 = (blk & 127) << 7;
    int tid  = threadIdx.x;
    int lane = tid & 63, wv = tid >> 6;
    int r = lane & 15, q = lane >> 4;
    int i_oc = wv >> 1, j_pos = wv & 1;

    floatx4 acc[4] = {};
    const unsigned short* xb = xt + ((size_t)b << 20);   // b*16384*64

    for (int k = 0; k < 9; ++k) {
        int ki = k / 3 - 1, kj = k % 3 - 1;
        __syncthreads();
        #pragma unroll 4
        for (int pi = 0; pi < 32; ++pi) {
            int p   = (wv << 5) + pi;
            int pos = pos0 + p;
            int y = pos >> 7, x = pos & 127;
            int sy = y + ki, sx = x + kj;
            unsigned short v = 0;
            if (sy >= 0 && sy < 128 && sx >= 0 && sx < 128)
                v = xb[(size_t)(((sy << 7) + sx) << 6) + lane];
            tile[p][lane] = v;
        }
        __syncthreads();
        #pragma unroll
        for (int ch = 0; ch < 2; ++ch) {
            short8 afrag = *(const short8*)&wpack27[((i_oc << 4) + r) * 576 + (k << 6) + (ch << 5) + (q << 3)];
            #pragma unroll
            for (int nt = 0; nt < 4; ++nt) {
                short8 bfrag = *(const short8*)&tile[(j_pos << 6) + (nt << 4) + r][(ch << 5) + (q << 3)];
                acc[nt] = __builtin_amdgcn_mfma_f32_16x16x32_bf16(afrag, bfrag, acc[nt], 0, 0, 0);
            }
        }
    }

    #pragma unroll
    for (int nt = 0; nt < 4; ++nt) {
        #pragma unroll
        for (int reg = 0; reg < 4; ++reg) {
            int oc = (i_oc << 4) + (q << 2) + reg;
            if (oc >= 27) continue;
            int pos = pos0 + (j_pos << 6) + (nt << 4) + r;
            float v = acc[nt][reg] + bias27[oc];
            int kk, comp;
            if (oc < 18) { kk = oc >> 1; comp = oc & 1; }
            else         { kk = oc - 18; comp = 2; v = 2.f / (1.f + __expf(-v)); }
            offP[(size_t)(((b * 9 + kk) * 3 + comp) << 14) + pos] = v;
        }
    }
}

// ---------------------------------------------------------------------------
// Kernel 4: main deformable conv. Block: 256 thr (4 waves), 64 positions,
// all 64 output channels. Per tap k: each wave gathers 16 positions
// (lanes = 64 channels, one coalesced 128B row per bilinear corner),
// blends with mask-folded wave-uniform weights, stores bf16 B-tile
// [64 pos][64 c] (stride 72) to LDS; then wave wv computes oc strip
// 16*wv via 2 K-chunks x 4 n-tile MFMAs. Epilogue: +bias, relu, store f32.
// ---------------------------------------------------------------------------
__global__ __launch_bounds__(256) void deform_main_k(const unsigned short* __restrict__ xt,
                                                     const unsigned short* __restrict__ wpackM,
                                                     const float* __restrict__ offP,
                                                     const float* __restrict__ bias,
                                                     float* __restrict__ out) {
    __shared__ unsigned short samp[64][72];
    int blk  = blockIdx.x;                          // 2048 = 8 b * 256
    int b    = blk >> 8;
    int pos0 = (blk & 255) << 6;
    int tid  = threadIdx.x;
    int lane = tid & 63, wv = tid >> 6;
    int r = lane & 15, q = lane >> 4;

    floatx4 acc[4] = {};
    const unsigned short* xb = xt + ((size_t)b << 20);

    for (int k = 0; k < 9; ++k) {
        float ky = (float)(k / 3 - 1), kx = (float)(k % 3 - 1);
        const float* offk = offP + ((size_t)((b * 9 + k) * 3) << 14);
        __syncthreads();
        #pragma unroll 4
        for (int pi = 0; pi < 16; ++pi) {
            int p   = (wv << 4) + pi;
            int pos = pos0 + p;
            float dy = offk[pos];
            float dx = offk[16384 + pos];
            float m  = offk[32768 + pos];
            float py = (float)(pos >> 7) + ky + dy;
            float px = (float)(pos & 127) + kx + dx;
            float y0f = floorf(py), x0f = floorf(px);
            int y0 = (int)y0f, x0 = (int)x0f;
            float wy1 = py - y0f, wx1 = px - x0f;
            float wy0 = 1.f - wy1, wx0 = 1.f - wx1;
            bool vy0 = (y0 >= 0) && (y0 < 128);
            bool vy1 = (y0 >= -1) && (y0 < 127);
            bool vx0 = (x0 >= 0) && (x0 < 128);
            bool vx1 = (x0 >= -1) && (x0 < 127);
            float w00 = (vy0 && vx0) ? m * wy0 * wx0 : 0.f;
            float w01 = (vy0 && vx1) ? m * wy0 * wx1 : 0.f;
            float w10 = (vy1 && vx0) ? m * wy1 * wx0 : 0.f;
            float w11 = (vy1 && vx1) ? m * wy1 * wx1 : 0.f;
            int y0c = min(max(y0, 0), 127),     y1c = min(max(y0 + 1, 0), 127);
            int x0c = min(max(x0, 0), 127),     x1c = min(max(x0 + 1, 0), 127);
            float v00 = bf2f(xb[(size_t)((((y0c << 7) + x0c) << 6)) + lane]);
            float v01 = bf2f(xb[(size_t)((((y0c << 7) + x1c) << 6)) + lane]);
            float v10 = bf2f(xb[(size_t)((((y1c << 7) + x0c) << 6)) + lane]);
            float v11 = bf2f(xb[(size_t)((((y1c << 7) + x1c) << 6)) + lane]);
            float s = w00 * v00 + w01 * v01 + w10 * v10 + w11 * v11;
            samp[p][lane] = f2bf(s);
        }
        __syncthreads();
        #pragma unroll
        for (int ch = 0; ch < 2; ++ch) {
            short8 afrag = *(const short8*)&wpackM[((wv << 4) + r) * 576 + (k << 6) + (ch << 5) + (q << 3)];
            #pragma unroll
            for (int nt = 0; nt < 4; ++nt) {
                short8 bfrag = *(const short8*)&samp[(nt << 4) + r][(ch << 5) + (q << 3)];
                acc[nt] = __builtin_amdgcn_mfma_f32_16x16x32_bf16(afrag, bfrag, acc[nt], 0, 0, 0);
            }
        }
    }

    #pragma unroll
    for (int nt = 0; nt < 4; ++nt) {
        #pragma unroll
        for (int reg = 0; reg < 4; ++reg) {
            int oc  = (wv << 4) + (q << 2) + reg;
            int pos = pos0 + (nt << 4) + r;
            float v = acc[nt][reg] + bias[oc];
            out[(size_t)(((b << 6) + oc) << 14) + pos] = fmaxf(v, 0.f);
        }
    }
}

// ---------------------------------------------------------------------------
extern "C" void kernel_launch(void* const* d_in, const int* in_sizes, int n_in,
                              void* d_out, int out_size, void* d_ws, size_t ws_size,
                              hipStream_t stream) {
    const float* data  = (const float*)d_in[0];
    const float* w     = (const float*)d_in[1];
    const float* bias  = (const float*)d_in[2];
    const float* w_off = (const float*)d_in[3];
    const float* b_off = (const float*)d_in[4];
    const float* w_mod = (const float*)d_in[5];
    const float* b_mod = (const float*)d_in[6];
    float* out = (float*)d_out;

    char* ws = (char*)d_ws;
    unsigned short* dataT   = (unsigned short*)(ws + OFF_DATAT);
    float*          offP    = (float*)(ws + OFF_OFFP);
    unsigned short* wpackM  = (unsigned short*)(ws + OFF_WM);
    unsigned short* wpack27 = (unsigned short*)(ws + OFF_W27);
    float*          bias27  = (float*)(ws + OFF_B27);

    pack_weights_k<<<216, 256, 0, stream>>>(w, w_off, w_mod, b_off, b_mod,
                                            wpackM, wpack27, bias27);
    transpose_k<<<2048, 256, 0, stream>>>(data, dataT);
    conv27_k<<<1024, 256, 0, stream>>>(dataT, wpack27, bias27, offP);
    deform_main_k<<<2048, 256, 0, stream>>>(dataT, wpackM, offP, bias, out);
}

// Round 2
// 209.942 us; speedup vs baseline: 1.5316x; 1.5316x over previous
//
#include <hip/hip_runtime.h>
#include <cstdint>

// ---------------------------------------------------------------------------
// SingleDeformConv on MI355X (gfx950)
// data (8,64,128,128) f32; w (64,64,3,3); b (64); w_off (18,64,3,3); b_off(18);
// w_mod (9,64,3,3); b_mod (9).  out = relu(deform_conv(...)) (8,64,128,128) f32
//
// R1: deform_main gather params (bilinear weights + corner offsets) were
// computed redundantly in all 64 lanes (75% of VALU time). Now precomputed
// once per (tap,pos) in a phase-0 pass into LDS; gather loop reads them via
// broadcast ds_read_b128 and loads 2 channels/lane (dword). conv27 now stages
// a single 3-row halo tile (1 staging pass, 2 syncs) instead of 9 passes.
// ---------------------------------------------------------------------------

typedef __attribute__((ext_vector_type(8))) short short8;
typedef __attribute__((ext_vector_type(4))) float floatx4;

__device__ __forceinline__ unsigned short f2bf(float x) {
    unsigned int u = __float_as_uint(x);
    u += 0x7fffu + ((u >> 16) & 1u);           // round-to-nearest-even
    return (unsigned short)(u >> 16);
}
__device__ __forceinline__ float bf2f(unsigned short s) {
    return __uint_as_float(((unsigned int)s) << 16);
}
// low/high bf16 of a packed dword -> float
__device__ __forceinline__ float bflo(unsigned int u) { return __uint_as_float(u << 16); }
__device__ __forceinline__ float bfhi(unsigned int u) { return __uint_as_float(u & 0xffff0000u); }
// pack two floats -> bf16x2 dword (RNE)
__device__ __forceinline__ unsigned int pack2bf(float lo, float hi) {
    unsigned int ul = __float_as_uint(lo); ul += 0x7fffu + ((ul >> 16) & 1u);
    unsigned int uh = __float_as_uint(hi); uh += 0x7fffu + ((uh >> 16) & 1u);
    return __builtin_amdgcn_perm(uh, ul, 0x07060302u);  // [lo.b2,lo.b3,hi.b2,hi.b3]
}

// Workspace layout (bytes)
#define OFF_DATAT 0u               // [8][16384][64] bf16  = 16777216 B
#define OFF_OFFP  16777216u        // [8][9][3][16384] f32 = 14155776 B (dy,dx,mask)
#define OFF_WM    30932992u        // [64][576] bf16       = 73728 B
#define OFF_W27   31006720u        // [32][576] bf16       = 36864 B
#define OFF_B27   31043584u        // [32] f32             = 128 B
// total 31043712 B

// ---------------------------------------------------------------------------
// Kernel 1: pack weights to bf16, K index = k*64 + c  (k = ky*3+kx)
// ---------------------------------------------------------------------------
__global__ void pack_weights_k(const float* __restrict__ w,
                               const float* __restrict__ w_off,
                               const float* __restrict__ w_mod,
                               const float* __restrict__ b_off,
                               const float* __restrict__ b_mod,
                               unsigned short* __restrict__ wpackM,
                               unsigned short* __restrict__ wpack27,
                               float* __restrict__ bias27) {
    int t = blockIdx.x * 256 + threadIdx.x;
    if (t < 64 * 576) {
        int o = t / 576, kk = t % 576;
        int k = kk >> 6, c = kk & 63;
        wpackM[t] = f2bf(w[(o * 64 + c) * 9 + k]);
        return;
    }
    t -= 64 * 576;
    if (t < 32 * 576) {
        int o = t / 576, kk = t % 576;
        int k = kk >> 6, c = kk & 63;
        float v = 0.f;
        if (o < 18)      v = w_off[(o * 64 + c) * 9 + k];
        else if (o < 27) v = w_mod[((o - 18) * 64 + c) * 9 + k];
        wpack27[t] = f2bf(v);
        if (kk == 0) bias27[o] = (o < 18) ? b_off[o] : (o < 27 ? b_mod[o - 18] : 0.f);
    }
}

// ---------------------------------------------------------------------------
// Kernel 2: NCHW f32 -> NHWC bf16 transpose.  64x64 tile per block.
// ---------------------------------------------------------------------------
__global__ __launch_bounds__(256) void transpose_k(const float* __restrict__ x,
                                                   unsigned short* __restrict__ xt) {
    __shared__ float tile[64][65];                 // +1 pad: conflict-free transpose
    int blk  = blockIdx.x;                         // 2048 = 8 b * 256 tiles
    int b    = blk >> 8;
    int pos0 = (blk & 255) << 6;
    int lane = threadIdx.x & 63;
    int g    = threadIdx.x >> 6;
    for (int c = g; c < 64; c += 4)
        tile[c][lane] = x[(((b << 6) + c) << 14) + pos0 + lane];   // coalesced 256B
    __syncthreads();
    for (int pr = g; pr < 64; pr += 4)
        xt[(size_t)(((b << 14) + pos0 + pr) << 6) + lane] = f2bf(tile[lane][pr]); // coalesced 128B
}

// ---------------------------------------------------------------------------
// Kernel 3: offset/mask conv (27 ch, padded to 32) — implicit GEMM, bf16 MFMA.
// Block: 256 thr (4 waves), one output row y (128 positions), batch b.
// Single staging pass: halo tile [3 rows][130 cols][64 c] (zero-padded cols),
// dword (2ch) staged by 8 half-waves. Then 9 taps x 2 K-chunks x 4 n-tiles
// MFMA reading shifted LDS windows. 2 syncs total (was 18).
// ---------------------------------------------------------------------------
__global__ __launch_bounds__(256) void conv27_k(const unsigned short* __restrict__ xt,
                                                const unsigned short* __restrict__ wpack27,
                                                const float* __restrict__ bias27,
                                                float* __restrict__ offP) {
    __shared__ unsigned short tile[3][130][72];     // 56160 B
    int blk  = blockIdx.x;                          // 1024 = 8 b * 128 rows
    int b    = blk >> 7;
    int y    = blk & 127;
    int pos0 = y << 7;
    int tid  = threadIdx.x;
    int lane = tid & 63, wv = tid >> 6;
    int r = lane & 15, q = lane >> 4;
    int i_oc = wv >> 1, j_pos = wv & 1;

    const unsigned short* xb = xt + ((size_t)b << 20);   // b*16384*64

    // ---- stage halo tile: 390 slots (3 rows x 130 cols), dword per lane ----
    {
        int hw = tid >> 5, c2 = tid & 31;           // 8 half-waves, 32 ch-pairs
        for (int s = hw; s < 390; s += 8) {
            int r3 = s / 130, col = s - r3 * 130;
            int sy = y + r3 - 1, sx = col - 1;
            unsigned int v = 0;
            if (sy >= 0 && sy < 128 && sx >= 0 && sx < 128)
                v = *(const unsigned int*)&xb[(size_t)(((sy << 7) + sx) << 6) + (c2 << 1)];
            *(unsigned int*)&tile[r3][col][c2 << 1] = v;
        }
    }
    __syncthreads();

    // ---- MFMA: 9 taps x 2 ch-chunks x 4 n-tiles ----
    floatx4 acc[4] = {};
    #pragma unroll
    for (int k = 0; k < 9; ++k) {
        int ki = k / 3, kj = k % 3;                 // tile row, col shift
        #pragma unroll
        for (int ch = 0; ch < 2; ++ch) {
            short8 afrag = *(const short8*)&wpack27[((i_oc << 4) + r) * 576 + (k << 6) + (ch << 5) + (q << 3)];
            #pragma unroll
            for (int nt = 0; nt < 4; ++nt) {
                int xcol = (j_pos << 6) + (nt << 4) + r + kj;   // +kj, halo col offset +1-1
                short8 bfrag = *(const short8*)&tile[ki][xcol][(ch << 5) + (q << 3)];
                acc[nt] = __builtin_amdgcn_mfma_f32_16x16x32_bf16(afrag, bfrag, acc[nt], 0, 0, 0);
            }
        }
    }

    #pragma unroll
    for (int nt = 0; nt < 4; ++nt) {
        #pragma unroll
        for (int reg = 0; reg < 4; ++reg) {
            int oc = (i_oc << 4) + (q << 2) + reg;
            if (oc >= 27) continue;
            int pos = pos0 + (j_pos << 6) + (nt << 4) + r;
            float v = acc[nt][reg] + bias27[oc];
            int kk, comp;
            if (oc < 18) { kk = oc >> 1; comp = oc & 1; }
            else         { kk = oc - 18; comp = 2; v = 2.f / (1.f + __expf(-v)); }
            offP[(size_t)(((b * 9 + kk) * 3 + comp) << 14) + pos] = v;
        }
    }
}

// ---------------------------------------------------------------------------
// Kernel 4: main deformable conv. Block: 256 thr (4 waves), 64 positions.
// Phase 0: 576 (tap,pos) param entries computed ONCE each (weights mask-folded,
// corner byte-offsets pre-scaled by 128) -> LDS. Per tap k: each wave gathers
// its 16 positions 2-at-a-time (half-wave = 1 position, lane = 2 channels,
// dword loads), blends, packs bf16x2 to LDS B-tile; then MFMA. Params read
// via broadcast ds_read_b128 — no redundant per-lane weight math.
// ---------------------------------------------------------------------------
__global__ __launch_bounds__(256) void deform_main_k(const unsigned short* __restrict__ xt,
                                                     const unsigned short* __restrict__ wpackM,
                                                     const float* __restrict__ offP,
                                                     const float* __restrict__ bias,
                                                     float* __restrict__ out) {
    __shared__ int4   pOff[576];                    // 9216 B  corner byte-offsets
    __shared__ float4 pW[576];                      // 9216 B  mask-folded weights
    __shared__ unsigned short samp[64][72];         // 9216 B  B-tile
    int blk  = blockIdx.x;                          // 2048 = 8 b * 256
    int b    = blk >> 8;
    int pos0 = (blk & 255) << 6;
    int tid  = threadIdx.x;
    int lane = tid & 63, wv = tid >> 6;
    int r = lane & 15, q = lane >> 4;
    int half = lane >> 5, c2 = lane & 31;

    const char* xbb = (const char*)(xt + ((size_t)b << 20));

    // ---- phase 0: params, one thread per (tap,pos) entry ----
    for (int e = tid; e < 576; e += 256) {
        int k = e >> 6, p = e & 63;
        int pos = pos0 + p;
        const float* offk = offP + ((size_t)((b * 9 + k) * 3) << 14);
        float dy = offk[pos];
        float dx = offk[16384 + pos];
        float m  = offk[32768 + pos];
        float py = (float)(pos >> 7) + (float)(k / 3 - 1) + dy;
        float px = (float)(pos & 127) + (float)(k % 3 - 1) + dx;
        float y0f = floorf(py), x0f = floorf(px);
        int y0 = (int)y0f, x0 = (int)x0f;
        float wy1 = py - y0f, wx1 = px - x0f;
        float wy0 = 1.f - wy1, wx0 = 1.f - wx1;
        bool vy0 = (y0 >= 0) && (y0 < 128);
        bool vy1 = (y0 >= -1) && (y0 < 127);
        bool vx0 = (x0 >= 0) && (x0 < 128);
        bool vx1 = (x0 >= -1) && (x0 < 127);
        float w00 = (vy0 && vx0) ? m * wy0 * wx0 : 0.f;
        float w01 = (vy0 && vx1) ? m * wy0 * wx1 : 0.f;
        float w10 = (vy1 && vx0) ? m * wy1 * wx0 : 0.f;
        float w11 = (vy1 && vx1) ? m * wy1 * wx1 : 0.f;
        int y0c = min(max(y0, 0), 127), y1c = min(max(y0 + 1, 0), 127);
        int x0c = min(max(x0, 0), 127), x1c = min(max(x0 + 1, 0), 127);
        pOff[e] = make_int4(((y0c << 7) + x0c) << 7, ((y0c << 7) + x1c) << 7,
                            ((y1c << 7) + x0c) << 7, ((y1c << 7) + x1c) << 7);
        pW[e] = make_float4(w00, w01, w10, w11);
    }

    floatx4 acc[4] = {};
    const char* xp = xbb + (c2 << 2);               // per-lane channel-pair base

    for (int k = 0; k < 9; ++k) {
        __syncthreads();                            // phase-0 done / samp free
        #pragma unroll 2
        for (int i = 0; i < 8; ++i) {
            int p2 = (wv << 4) + (i << 1) + half;   // this half-wave's position
            int e  = (k << 6) + p2;
            int4   io = pOff[e];                    // broadcast ds_read_b128
            float4 fw = pW[e];
            unsigned int u00 = *(const unsigned int*)(xp + io.x);
            unsigned int u01 = *(const unsigned int*)(xp + io.y);
            unsigned int u10 = *(const unsigned int*)(xp + io.z);
            unsigned int u11 = *(const unsigned int*)(xp + io.w);
            float slo = fw.x * bflo(u00) + fw.y * bflo(u01) + fw.z * bflo(u10) + fw.w * bflo(u11);
            float shi = fw.x * bfhi(u00) + fw.y * bfhi(u01) + fw.z * bfhi(u10) + fw.w * bfhi(u11);
            *(unsigned int*)&samp[p2][c2 << 1] = pack2bf(slo, shi);
        }
        __syncthreads();
        #pragma unroll
        for (int ch = 0; ch < 2; ++ch) {
            short8 afrag = *(const short8*)&wpackM[((wv << 4) + r) * 576 + (k << 6) + (ch << 5) + (q << 3)];
            #pragma unroll
            for (int nt = 0; nt < 4; ++nt) {
                short8 bfrag = *(const short8*)&samp[(nt << 4) + r][(ch << 5) + (q << 3)];
                acc[nt] = __builtin_amdgcn_mfma_f32_16x16x32_bf16(afrag, bfrag, acc[nt], 0, 0, 0);
            }
        }
    }

    #pragma unroll
    for (int nt = 0; nt < 4; ++nt) {
        #pragma unroll
        for (int reg = 0; reg < 4; ++reg) {
            int oc  = (wv << 4) + (q << 2) + reg;
            int pos = pos0 + (nt << 4) + r;
            float v = acc[nt][reg] + bias[oc];
            out[(size_t)(((b << 6) + oc) << 14) + pos] = fmaxf(v, 0.f);
        }
    }
}

// ---------------------------------------------------------------------------
extern "C" void kernel_launch(void* const* d_in, const int* in_sizes, int n_in,
                              void* d_out, int out_size, void* d_ws, size_t ws_size,
                              hipStream_t stream) {
    const float* data  = (const float*)d_in[0];
    const float* w     = (const float*)d_in[1];
    const float* bias  = (const float*)d_in[2];
    const float* w_off = (const float*)d_in[3];
    const float* b_off = (const float*)d_in[4];
    const float* w_mod = (const float*)d_in[5];
    const float* b_mod = (const float*)d_in[6];
    float* out = (float*)d_out;

    char* ws = (char*)d_ws;
    unsigned short* dataT   = (unsigned short*)(ws + OFF_DATAT);
    float*          offP    = (float*)(ws + OFF_OFFP);
    unsigned short* wpackM  = (unsigned short*)(ws + OFF_WM);
    unsigned short* wpack27 = (unsigned short*)(ws + OFF_W27);
    float*          bias27  = (float*)(ws + OFF_B27);

    pack_weights_k<<<216, 256, 0, stream>>>(w, w_off, w_mod, b_off, b_mod,
                                            wpackM, wpack27, bias27);
    transpose_k<<<2048, 256, 0, stream>>>(data, dataT);
    conv27_k<<<1024, 256, 0, stream>>>(dataT, wpack27, bias27, offP);
    deform_main_k<<<2048, 256, 0, stream>>>(dataT, wpackM, offP, bias, out);
}

// Round 3
// 172.550 us; speedup vs baseline: 1.8635x; 1.2167x over previous
//
#include <hip/hip_runtime.h>
#include <cstdint>

// ---------------------------------------------------------------------------
// SingleDeformConv on MI355X (gfx950)
// data (8,64,128,128) f32; w (64,64,3,3); b (64); w_off (18,64,3,3); b_off(18);
// w_mod (9,64,3,3); b_mod (9).  out = relu(deform_conv(...)) (8,64,128,128) f32
//
// R2 -> R3: deform_main gather widened to 8 ch/lane (b128 corner loads,
// 4x fewer VMEM/LDS issues). conv27 restructured to 2x64 patches with 38KB
// halo tile (4 blocks/CU), fully-coalesced b128 staging, bfrag shared across
// oc strips. transpose stores dword-packed bf16x2.
// ---------------------------------------------------------------------------

typedef __attribute__((ext_vector_type(8))) short short8;
typedef __attribute__((ext_vector_type(4))) float floatx4;

__device__ __forceinline__ unsigned short f2bf(float x) {
    unsigned int u = __float_as_uint(x);
    u += 0x7fffu + ((u >> 16) & 1u);           // round-to-nearest-even
    return (unsigned short)(u >> 16);
}
// low/high bf16 of a packed dword -> float
__device__ __forceinline__ float bflo(unsigned int u) { return __uint_as_float(u << 16); }
__device__ __forceinline__ float bfhi(unsigned int u) { return __uint_as_float(u & 0xffff0000u); }
// pack two floats -> bf16x2 dword (RNE)
__device__ __forceinline__ unsigned int pack2bf(float lo, float hi) {
    unsigned int ul = __float_as_uint(lo); ul += 0x7fffu + ((ul >> 16) & 1u);
    unsigned int uh = __float_as_uint(hi); uh += 0x7fffu + ((uh >> 16) & 1u);
    return __builtin_amdgcn_perm(uh, ul, 0x07060302u);  // [lo.b2,lo.b3,hi.b2,hi.b3]
}
// blend one bf16x2 dword from 4 corners with weights fw -> packed bf16x2
__device__ __forceinline__ unsigned int blend2(unsigned int a, unsigned int b,
                                               unsigned int c, unsigned int d,
                                               float4 fw) {
    float lo = fw.x * bflo(a) + fw.y * bflo(b) + fw.z * bflo(c) + fw.w * bflo(d);
    float hi = fw.x * bfhi(a) + fw.y * bfhi(b) + fw.z * bfhi(c) + fw.w * bfhi(d);
    return pack2bf(lo, hi);
}

// Workspace layout (bytes)
#define OFF_DATAT 0u               // [8][16384][64] bf16  = 16777216 B
#define OFF_OFFP  16777216u        // [8][9][3][16384] f32 = 14155776 B (dy,dx,mask)
#define OFF_WM    30932992u        // [64][576] bf16       = 73728 B
#define OFF_W27   31006720u        // [32][576] bf16       = 36864 B
#define OFF_B27   31043584u        // [32] f32             = 128 B
// total 31043712 B

// ---------------------------------------------------------------------------
// Kernel 1: pack weights to bf16, K index = k*64 + c  (k = ky*3+kx)
// ---------------------------------------------------------------------------
__global__ void pack_weights_k(const float* __restrict__ w,
                               const float* __restrict__ w_off,
                               const float* __restrict__ w_mod,
                               const float* __restrict__ b_off,
                               const float* __restrict__ b_mod,
                               unsigned short* __restrict__ wpackM,
                               unsigned short* __restrict__ wpack27,
                               float* __restrict__ bias27) {
    int t = blockIdx.x * 256 + threadIdx.x;
    if (t < 64 * 576) {
        int o = t / 576, kk = t % 576;
        int k = kk >> 6, c = kk & 63;
        wpackM[t] = f2bf(w[(o * 64 + c) * 9 + k]);
        return;
    }
    t -= 64 * 576;
    if (t < 32 * 576) {
        int o = t / 576, kk = t % 576;
        int k = kk >> 6, c = kk & 63;
        float v = 0.f;
        if (o < 18)      v = w_off[(o * 64 + c) * 9 + k];
        else if (o < 27) v = w_mod[((o - 18) * 64 + c) * 9 + k];
        wpack27[t] = f2bf(v);
        if (kk == 0) bias27[o] = (o < 18) ? b_off[o] : (o < 27 ? b_mod[o - 18] : 0.f);
    }
}

// ---------------------------------------------------------------------------
// Kernel 2: NCHW f32 -> NHWC bf16 transpose.  64x64 tile per block.
// ---------------------------------------------------------------------------
__global__ __launch_bounds__(256) void transpose_k(const float* __restrict__ x,
                                                   unsigned short* __restrict__ xt) {
    __shared__ float tile[64][65];                 // +1 pad: conflict-free transpose
    int blk  = blockIdx.x;                         // 2048 = 8 b * 256 tiles
    int b    = blk >> 8;
    int pos0 = (blk & 255) << 6;
    int lane = threadIdx.x & 63;
    int g    = threadIdx.x >> 6;
    for (int c = g; c < 64; c += 4)
        tile[c][lane] = x[(((b << 6) + c) << 14) + pos0 + lane];   // coalesced 256B
    __syncthreads();
    int c2 = lane & 31;
    for (int i = g; i < 32; i += 4) {              // 8 iters, dword stores 256B/wave
        int pr = (i << 1) + (lane >> 5);
        unsigned int d = pack2bf(tile[c2 << 1][pr], tile[(c2 << 1) + 1][pr]);
        *(unsigned int*)&xt[((size_t)((b << 14) + pos0 + pr) << 6) + (c2 << 1)] = d;
    }
}

// ---------------------------------------------------------------------------
// Kernel 3: offset/mask conv (27 ch, padded to 32) — implicit GEMM, bf16 MFMA.
// Block: 256 thr (4 waves), 2x64 position patch. Halo tile [4 rows][66 cols]
// [64 c] bf16 (stride 72) = 38016 B -> 4 blocks/CU. Staging: b128/lane,
// 1KB/wave contiguous, 12 iters. MFMA: 9 taps x 2 ch x 2 rows x 2 oc-strips,
// bfrag shared across strips. Epilogue: dy/dx + bias; mask = 2*sigmoid.
// ---------------------------------------------------------------------------
__global__ __launch_bounds__(256) void conv27_k(const unsigned short* __restrict__ xt,
                                                const unsigned short* __restrict__ wpack27,
                                                const float* __restrict__ bias27,
                                                float* __restrict__ offP) {
    __shared__ unsigned short tile[4][66][72];      // 38016 B
    int blk   = blockIdx.x;                         // 1024 = 8 b * 128 patches
    int b     = blk >> 7;
    int patch = blk & 127;
    int m     = patch >> 1;                         // row pair 0..63
    int h     = patch & 1;                          // col half 0..1
    int tid   = threadIdx.x;
    int lane  = tid & 63, wv = tid >> 6;
    int r = lane & 15, q = lane >> 4;

    const unsigned short* xb = xt + ((size_t)b << 20);   // b*16384*64

    // ---- stage halo: 4 rows x 66 cols, b128 per lane (8 lanes per col) ----
    {
        int g = tid >> 3, j = tid & 7;              // 32 col-groups, 8 ch-chunks
        #pragma unroll
        for (int rr = 0; rr < 4; ++rr) {
            int sy = (m << 1) + rr - 1;
            #pragma unroll
            for (int ci = 0; ci < 3; ++ci) {
                int col = g + (ci << 5);
                if (col < 66) {
                    int sx = (h << 6) + col - 1;
                    uint4 v = {0u, 0u, 0u, 0u};
                    if (sy >= 0 && sy < 128 && sx >= 0 && sx < 128)
                        v = *(const uint4*)&xb[(size_t)(((sy << 7) + sx) << 6) + (j << 3)];
                    *(uint4*)&tile[rr][col][j << 3] = v;
                }
            }
        }
    }
    __syncthreads();

    // ---- MFMA: 9 taps x 2 ch-chunks x 2 tile-rows, 2 oc strips ----
    floatx4 acc[4] = {};                            // [strip*2 + tr]
    #pragma unroll
    for (int k = 0; k < 9; ++k) {
        int ki = k / 3, kj = k % 3;
        #pragma unroll
        for (int ch = 0; ch < 2; ++ch) {
            short8 a0 = *(const short8*)&wpack27[(r)      * 576 + (k << 6) + (ch << 5) + (q << 3)];
            short8 a1 = *(const short8*)&wpack27[(16 + r) * 576 + (k << 6) + (ch << 5) + (q << 3)];
            #pragma unroll
            for (int tr = 0; tr < 2; ++tr) {
                short8 bfrag = *(const short8*)&tile[tr + ki][(wv << 4) + r + kj][(ch << 5) + (q << 3)];
                acc[0 + tr] = __builtin_amdgcn_mfma_f32_16x16x32_bf16(a0, bfrag, acc[0 + tr], 0, 0, 0);
                acc[2 + tr] = __builtin_amdgcn_mfma_f32_16x16x32_bf16(a1, bfrag, acc[2 + tr], 0, 0, 0);
            }
        }
    }

    #pragma unroll
    for (int s = 0; s < 2; ++s) {
        #pragma unroll
        for (int tr = 0; tr < 2; ++tr) {
            #pragma unroll
            for (int reg = 0; reg < 4; ++reg) {
                int oc = (s << 4) + (q << 2) + reg;
                if (oc >= 27) continue;
                int pos = (((m << 1) + tr) << 7) + (h << 6) + (wv << 4) + r;
                float v = acc[(s << 1) + tr][reg] + bias27[oc];
                int kk, comp;
                if (oc < 18) { kk = oc >> 1; comp = oc & 1; }
                else         { kk = oc - 18; comp = 2; v = 2.f / (1.f + __expf(-v)); }
                offP[(size_t)(((b * 9 + kk) * 3 + comp) << 14) + pos] = v;
            }
        }
    }
}

// ---------------------------------------------------------------------------
// Kernel 4: main deformable conv. Block: 256 thr (4 waves), 64 positions.
// Phase 0: 576 (tap,pos) param entries once each -> LDS (int4 corner offsets,
// float4 mask-folded weights). Gather: lane = 8 channels (b128 corner loads),
// 8 lanes/position, 2 iters/tap/wave. Blend in f32, pack bf16x2, b128 LDS
// store (bank-balanced). MFMA per tap; epilogue +bias, relu.
// ---------------------------------------------------------------------------
__global__ __launch_bounds__(256) void deform_main_k(const unsigned short* __restrict__ xt,
                                                     const unsigned short* __restrict__ wpackM,
                                                     const float* __restrict__ offP,
                                                     const float* __restrict__ bias,
                                                     float* __restrict__ out) {
    __shared__ int4   pOff[576];                    // 9216 B  corner byte-offsets
    __shared__ float4 pW[576];                      // 9216 B  mask-folded weights
    __shared__ unsigned short samp[64][72];         // 9216 B  B-tile
    int blk  = blockIdx.x;                          // 2048 = 8 b * 256
    int b    = blk >> 8;
    int pos0 = (blk & 255) << 6;
    int tid  = threadIdx.x;
    int lane = tid & 63, wv = tid >> 6;
    int r = lane & 15, q = lane >> 4;
    int pg = lane >> 3;                             // position subgroup 0..7
    int j8 = lane & 7;                              // channel chunk (8 bf16 = 16B)

    const char* xbb = (const char*)(xt + ((size_t)b << 20));

    // ---- phase 0: params, one thread per (tap,pos) entry ----
    for (int e = tid; e < 576; e += 256) {
        int k = e >> 6, p = e & 63;
        int pos = pos0 + p;
        const float* offk = offP + ((size_t)((b * 9 + k) * 3) << 14);
        float dy = offk[pos];
        float dx = offk[16384 + pos];
        float m  = offk[32768 + pos];
        float py = (float)(pos >> 7) + (float)(k / 3 - 1) + dy;
        float px = (float)(pos & 127) + (float)(k % 3 - 1) + dx;
        float y0f = floorf(py), x0f = floorf(px);
        int y0 = (int)y0f, x0 = (int)x0f;
        float wy1 = py - y0f, wx1 = px - x0f;
        float wy0 = 1.f - wy1, wx0 = 1.f - wx1;
        bool vy0 = (y0 >= 0) && (y0 < 128);
        bool vy1 = (y0 >= -1) && (y0 < 127);
        bool vx0 = (x0 >= 0) && (x0 < 128);
        bool vx1 = (x0 >= -1) && (x0 < 127);
        float w00 = (vy0 && vx0) ? m * wy0 * wx0 : 0.f;
        float w01 = (vy0 && vx1) ? m * wy0 * wx1 : 0.f;
        float w10 = (vy1 && vx0) ? m * wy1 * wx0 : 0.f;
        float w11 = (vy1 && vx1) ? m * wy1 * wx1 : 0.f;
        int y0c = min(max(y0, 0), 127), y1c = min(max(y0 + 1, 0), 127);
        int x0c = min(max(x0, 0), 127), x1c = min(max(x0 + 1, 0), 127);
        pOff[e] = make_int4(((y0c << 7) + x0c) << 7, ((y0c << 7) + x1c) << 7,
                            ((y1c << 7) + x0c) << 7, ((y1c << 7) + x1c) << 7);
        pW[e] = make_float4(w00, w01, w10, w11);
    }

    floatx4 acc[4] = {};
    const char* xp = xbb + (j8 << 4);               // per-lane channel-chunk base

    for (int k = 0; k < 9; ++k) {
        __syncthreads();                            // phase-0 done / samp free
        #pragma unroll
        for (int i = 0; i < 2; ++i) {
            int p = (wv << 4) + (i << 3) + pg;      // this lane-group's position
            int e = (k << 6) + p;
            int4   io = pOff[e];                    // broadcast ds_read_b128
            float4 fw = pW[e];
            uint4 u00 = *(const uint4*)(xp + io.x);
            uint4 u01 = *(const uint4*)(xp + io.y);
            uint4 u10 = *(const uint4*)(xp + io.z);
            uint4 u11 = *(const uint4*)(xp + io.w);
            uint4 o4;
            o4.x = blend2(u00.x, u01.x, u10.x, u11.x, fw);
            o4.y = blend2(u00.y, u01.y, u10.y, u11.y, fw);
            o4.z = blend2(u00.z, u01.z, u10.z, u11.z, fw);
            o4.w = blend2(u00.w, u01.w, u10.w, u11.w, fw);
            *(uint4*)&samp[p][j8 << 3] = o4;
        }
        __syncthreads();
        #pragma unroll
        for (int ch = 0; ch < 2; ++ch) {
            short8 afrag = *(const short8*)&wpackM[((wv << 4) + r) * 576 + (k << 6) + (ch << 5) + (q << 3)];
            #pragma unroll
            for (int nt = 0; nt < 4; ++nt) {
                short8 bfrag = *(const short8*)&samp[(nt << 4) + r][(ch << 5) + (q << 3)];
                acc[nt] = __builtin_amdgcn_mfma_f32_16x16x32_bf16(afrag, bfrag, acc[nt], 0, 0, 0);
            }
        }
    }

    #pragma unroll
    for (int nt = 0; nt < 4; ++nt) {
        #pragma unroll
        for (int reg = 0; reg < 4; ++reg) {
            int oc  = (wv << 4) + (q << 2) + reg;
            int pos = pos0 + (nt << 4) + r;
            float v = acc[nt][reg] + bias[oc];
            out[(size_t)(((b << 6) + oc) << 14) + pos] = fmaxf(v, 0.f);
        }
    }
}

// ---------------------------------------------------------------------------
extern "C" void kernel_launch(void* const* d_in, const int* in_sizes, int n_in,
                              void* d_out, int out_size, void* d_ws, size_t ws_size,
                              hipStream_t stream) {
    const float* data  = (const float*)d_in[0];
    const float* w     = (const float*)d_in[1];
    const float* bias  = (const float*)d_in[2];
    const float* w_off = (const float*)d_in[3];
    const float* b_off = (const float*)d_in[4];
    const float* w_mod = (const float*)d_in[5];
    const float* b_mod = (const float*)d_in[6];
    float* out = (float*)d_out;

    char* ws = (char*)d_ws;
    unsigned short* dataT   = (unsigned short*)(ws + OFF_DATAT);
    float*          offP    = (float*)(ws + OFF_OFFP);
    unsigned short* wpackM  = (unsigned short*)(ws + OFF_WM);
    unsigned short* wpack27 = (unsigned short*)(ws + OFF_W27);
    float*          bias27  = (float*)(ws + OFF_B27);

    pack_weights_k<<<216, 256, 0, stream>>>(w, w_off, w_mod, b_off, b_mod,
                                            wpackM, wpack27, bias27);
    transpose_k<<<2048, 256, 0, stream>>>(data, dataT);
    conv27_k<<<1024, 256, 0, stream>>>(dataT, wpack27, bias27, offP);
    deform_main_k<<<2048, 256, 0, stream>>>(dataT, wpackM, offP, bias, out);
}

// Round 4
// 165.109 us; speedup vs baseline: 1.9475x; 1.0451x over previous
//
#include <hip/hip_runtime.h>
#include <hip/hip_bf16.h>
#include <cstdint>

// ---------------------------------------------------------------------------
// SingleDeformConv on MI355X (gfx950)
// data (8,64,128,128) f32; w (64,64,3,3); b (64); w_off (18,64,3,3); b_off(18);
// w_mod (9,64,3,3); b_mod (9).  out = relu(deform_conv(...)) (8,64,128,128) f32
//
// R3 -> R4 (deform_main only):
//  * blend math on float2 vectors -> v_pk_fma_f32 (half the scalar FMA/unpack)
//  * samp double-buffered; corner loads + A-frags for tap k+1 issued before
//    the barrier; blend after MFMA(k). 10 syncs/block instead of 18.
// ---------------------------------------------------------------------------

typedef __attribute__((ext_vector_type(8))) short short8;
typedef __attribute__((ext_vector_type(4))) float floatx4;
typedef __attribute__((ext_vector_type(2))) float floatx2;

__device__ __forceinline__ unsigned short f2bf(float x) {
    unsigned int u = __float_as_uint(x);
    u += 0x7fffu + ((u >> 16) & 1u);           // round-to-nearest-even
    return (unsigned short)(u >> 16);
}
// pack two floats -> bf16x2 dword (RNE)
__device__ __forceinline__ unsigned int pack2bf(float lo, float hi) {
    unsigned int ul = __float_as_uint(lo); ul += 0x7fffu + ((ul >> 16) & 1u);
    unsigned int uh = __float_as_uint(hi); uh += 0x7fffu + ((uh >> 16) & 1u);
    return __builtin_amdgcn_perm(uh, ul, 0x07060302u);  // [lo.b2,lo.b3,hi.b2,hi.b3]
}
// unpack bf16x2 dword -> float2 (lo, hi)
__device__ __forceinline__ floatx2 up2(unsigned int u) {
    floatx2 r;
    r.x = __uint_as_float(u << 16);
    r.y = __uint_as_float(u & 0xffff0000u);
    return r;
}
// blend one bf16x2 dword from 4 corners with weights fw -> packed bf16x2
// (float2 math -> v_pk_fma_f32; RNE pack identical to pack2bf)
__device__ __forceinline__ unsigned int blend2pk(unsigned int a, unsigned int b,
                                                 unsigned int c, unsigned int d,
                                                 float4 fw) {
    floatx2 s = up2(a) * fw.x;
    s += up2(b) * fw.y;
    s += up2(c) * fw.z;
    s += up2(d) * fw.w;
    __hip_bfloat162 h = __float22bfloat162_rn(make_float2(s.x, s.y));
    return *(unsigned int*)&h;
}

// Workspace layout (bytes)
#define OFF_DATAT 0u               // [8][16384][64] bf16  = 16777216 B
#define OFF_OFFP  16777216u        // [8][9][3][16384] f32 = 14155776 B (dy,dx,mask)
#define OFF_WM    30932992u        // [64][576] bf16       = 73728 B
#define OFF_W27   31006720u        // [32][576] bf16       = 36864 B
#define OFF_B27   31043584u        // [32] f32             = 128 B
// total 31043712 B

// ---------------------------------------------------------------------------
// Kernel 1: pack weights to bf16, K index = k*64 + c  (k = ky*3+kx)
// ---------------------------------------------------------------------------
__global__ void pack_weights_k(const float* __restrict__ w,
                               const float* __restrict__ w_off,
                               const float* __restrict__ w_mod,
                               const float* __restrict__ b_off,
                               const float* __restrict__ b_mod,
                               unsigned short* __restrict__ wpackM,
                               unsigned short* __restrict__ wpack27,
                               float* __restrict__ bias27) {
    int t = blockIdx.x * 256 + threadIdx.x;
    if (t < 64 * 576) {
        int o = t / 576, kk = t % 576;
        int k = kk >> 6, c = kk & 63;
        wpackM[t] = f2bf(w[(o * 64 + c) * 9 + k]);
        return;
    }
    t -= 64 * 576;
    if (t < 32 * 576) {
        int o = t / 576, kk = t % 576;
        int k = kk >> 6, c = kk & 63;
        float v = 0.f;
        if (o < 18)      v = w_off[(o * 64 + c) * 9 + k];
        else if (o < 27) v = w_mod[((o - 18) * 64 + c) * 9 + k];
        wpack27[t] = f2bf(v);
        if (kk == 0) bias27[o] = (o < 18) ? b_off[o] : (o < 27 ? b_mod[o - 18] : 0.f);
    }
}

// ---------------------------------------------------------------------------
// Kernel 2: NCHW f32 -> NHWC bf16 transpose.  64x64 tile per block.
// ---------------------------------------------------------------------------
__global__ __launch_bounds__(256) void transpose_k(const float* __restrict__ x,
                                                   unsigned short* __restrict__ xt) {
    __shared__ float tile[64][65];                 // +1 pad: conflict-free transpose
    int blk  = blockIdx.x;                         // 2048 = 8 b * 256 tiles
    int b    = blk >> 8;
    int pos0 = (blk & 255) << 6;
    int lane = threadIdx.x & 63;
    int g    = threadIdx.x >> 6;
    for (int c = g; c < 64; c += 4)
        tile[c][lane] = x[(((b << 6) + c) << 14) + pos0 + lane];   // coalesced 256B
    __syncthreads();
    int c2 = lane & 31;
    for (int i = g; i < 32; i += 4) {              // 8 iters, dword stores 256B/wave
        int pr = (i << 1) + (lane >> 5);
        unsigned int d = pack2bf(tile[c2 << 1][pr], tile[(c2 << 1) + 1][pr]);
        *(unsigned int*)&xt[((size_t)((b << 14) + pos0 + pr) << 6) + (c2 << 1)] = d;
    }
}

// ---------------------------------------------------------------------------
// Kernel 3: offset/mask conv (27 ch, padded to 32) — implicit GEMM, bf16 MFMA.
// Block: 256 thr (4 waves), 2x64 position patch. Halo tile [4 rows][66 cols]
// [64 c] bf16 (stride 72) = 38016 B -> 4 blocks/CU. Staging: b128/lane,
// 1KB/wave contiguous. MFMA: 9 taps x 2 ch x 2 rows x 2 oc-strips,
// bfrag shared across strips. Epilogue: dy/dx + bias; mask = 2*sigmoid.
// ---------------------------------------------------------------------------
__global__ __launch_bounds__(256) void conv27_k(const unsigned short* __restrict__ xt,
                                                const unsigned short* __restrict__ wpack27,
                                                const float* __restrict__ bias27,
                                                float* __restrict__ offP) {
    __shared__ unsigned short tile[4][66][72];      // 38016 B
    int blk   = blockIdx.x;                         // 1024 = 8 b * 128 patches
    int b     = blk >> 7;
    int patch = blk & 127;
    int m     = patch >> 1;                         // row pair 0..63
    int h     = patch & 1;                          // col half 0..1
    int tid   = threadIdx.x;
    int lane  = tid & 63, wv = tid >> 6;
    int r = lane & 15, q = lane >> 4;

    const unsigned short* xb = xt + ((size_t)b << 20);   // b*16384*64

    // ---- stage halo: 4 rows x 66 cols, b128 per lane (8 lanes per col) ----
    {
        int g = tid >> 3, j = tid & 7;              // 32 col-groups, 8 ch-chunks
        #pragma unroll
        for (int rr = 0; rr < 4; ++rr) {
            int sy = (m << 1) + rr - 1;
            #pragma unroll
            for (int ci = 0; ci < 3; ++ci) {
                int col = g + (ci << 5);
                if (col < 66) {
                    int sx = (h << 6) + col - 1;
                    uint4 v = {0u, 0u, 0u, 0u};
                    if (sy >= 0 && sy < 128 && sx >= 0 && sx < 128)
                        v = *(const uint4*)&xb[(size_t)(((sy << 7) + sx) << 6) + (j << 3)];
                    *(uint4*)&tile[rr][col][j << 3] = v;
                }
            }
        }
    }
    __syncthreads();

    // ---- MFMA: 9 taps x 2 ch-chunks x 2 tile-rows, 2 oc strips ----
    floatx4 acc[4] = {};                            // [strip*2 + tr]
    #pragma unroll
    for (int k = 0; k < 9; ++k) {
        int ki = k / 3, kj = k % 3;
        #pragma unroll
        for (int ch = 0; ch < 2; ++ch) {
            short8 a0 = *(const short8*)&wpack27[(r)      * 576 + (k << 6) + (ch << 5) + (q << 3)];
            short8 a1 = *(const short8*)&wpack27[(16 + r) * 576 + (k << 6) + (ch << 5) + (q << 3)];
            #pragma unroll
            for (int tr = 0; tr < 2; ++tr) {
                short8 bfrag = *(const short8*)&tile[tr + ki][(wv << 4) + r + kj][(ch << 5) + (q << 3)];
                acc[0 + tr] = __builtin_amdgcn_mfma_f32_16x16x32_bf16(a0, bfrag, acc[0 + tr], 0, 0, 0);
                acc[2 + tr] = __builtin_amdgcn_mfma_f32_16x16x32_bf16(a1, bfrag, acc[2 + tr], 0, 0, 0);
            }
        }
    }

    #pragma unroll
    for (int s = 0; s < 2; ++s) {
        #pragma unroll
        for (int tr = 0; tr < 2; ++tr) {
            #pragma unroll
            for (int reg = 0; reg < 4; ++reg) {
                int oc = (s << 4) + (q << 2) + reg;
                if (oc >= 27) continue;
                int pos = (((m << 1) + tr) << 7) + (h << 6) + (wv << 4) + r;
                float v = acc[(s << 1) + tr][reg] + bias27[oc];
                int kk, comp;
                if (oc < 18) { kk = oc >> 1; comp = oc & 1; }
                else         { kk = oc - 18; comp = 2; v = 2.f / (1.f + __expf(-v)); }
                offP[(size_t)(((b * 9 + kk) * 3 + comp) << 14) + pos] = v;
            }
        }
    }
}

// ---------------------------------------------------------------------------
// Kernel 4: main deformable conv. Block: 256 thr (4 waves), 64 positions.
// Phase 0: 576 (tap,pos) params once each -> LDS. Pipelined k-loop with
// double-buffered samp: corner b128 loads + A-frags for tap k+1 issued
// before the barrier; MFMA(k) from samp[k&1]; blend(k+1) -> samp[(k+1)&1].
// One sync per tap. Blend uses float2 math (v_pk_fma_f32).
// ---------------------------------------------------------------------------
__global__ __launch_bounds__(256) void deform_main_k(const unsigned short* __restrict__ xt,
                                                     const unsigned short* __restrict__ wpackM,
                                                     const float* __restrict__ offP,
                                                     const float* __restrict__ bias,
                                                     float* __restrict__ out) {
    __shared__ int4   pOff[576];                    // 9216 B  corner byte-offsets
    __shared__ float4 pW[576];                      // 9216 B  mask-folded weights
    __shared__ unsigned short samp[2][64][72];      // 18432 B B-tile (double buf)
    int blk  = blockIdx.x;                          // 2048 = 8 b * 256
    int b    = blk >> 8;
    int pos0 = (blk & 255) << 6;
    int tid  = threadIdx.x;
    int lane = tid & 63, wv = tid >> 6;
    int r = lane & 15, q = lane >> 4;
    int pg = lane >> 3;                             // position subgroup 0..7
    int j8 = lane & 7;                              // channel chunk (8 bf16 = 16B)

    const char* xbb = (const char*)(xt + ((size_t)b << 20));

    // ---- phase 0: params, one thread per (tap,pos) entry ----
    for (int e = tid; e < 576; e += 256) {
        int k = e >> 6, p = e & 63;
        int pos = pos0 + p;
        const float* offk = offP + ((size_t)((b * 9 + k) * 3) << 14);
        float dy = offk[pos];
        float dx = offk[16384 + pos];
        float m  = offk[32768 + pos];
        float py = (float)(pos >> 7) + (float)(k / 3 - 1) + dy;
        float px = (float)(pos & 127) + (float)(k % 3 - 1) + dx;
        float y0f = floorf(py), x0f = floorf(px);
        int y0 = (int)y0f, x0 = (int)x0f;
        float wy1 = py - y0f, wx1 = px - x0f;
        float wy0 = 1.f - wy1, wx0 = 1.f - wx1;
        bool vy0 = (y0 >= 0) && (y0 < 128);
        bool vy1 = (y0 >= -1) && (y0 < 127);
        bool vx0 = (x0 >= 0) && (x0 < 128);
        bool vx1 = (x0 >= -1) && (x0 < 127);
        float w00 = (vy0 && vx0) ? m * wy0 * wx0 : 0.f;
        float w01 = (vy0 && vx1) ? m * wy0 * wx1 : 0.f;
        float w10 = (vy1 && vx0) ? m * wy1 * wx0 : 0.f;
        float w11 = (vy1 && vx1) ? m * wy1 * wx1 : 0.f;
        int y0c = min(max(y0, 0), 127), y1c = min(max(y0 + 1, 0), 127);
        int x0c = min(max(x0, 0), 127), x1c = min(max(x0 + 1, 0), 127);
        pOff[e] = make_int4(((y0c << 7) + x0c) << 7, ((y0c << 7) + x1c) << 7,
                            ((y1c << 7) + x0c) << 7, ((y1c << 7) + x1c) << 7);
        pW[e] = make_float4(w00, w01, w10, w11);
    }
    __syncthreads();                                // pOff/pW ready

    floatx4 acc[4] = {};
    const char* xp = xbb + (j8 << 4);               // per-lane channel-chunk base
    const unsigned short* wrow = wpackM + ((wv << 4) + r) * 576 + (q << 3);

    uint4  c00[2], c01[2], c10[2], c11[2];          // prefetched corners
    float4 cw[2];
    short8 afC[2], afN[2];                          // A-frags, current / next

    // issue tap-k corner loads + weights into registers (reads pOff only)
    auto issue = [&](int k) {
        #pragma unroll
        for (int i = 0; i < 2; ++i) {
            int e  = (k << 6) + (wv << 4) + (i << 3) + pg;
            int4   io = pOff[e];
            cw[i]  = pW[e];
            c00[i] = *(const uint4*)(xp + io.x);
            c01[i] = *(const uint4*)(xp + io.y);
            c10[i] = *(const uint4*)(xp + io.z);
            c11[i] = *(const uint4*)(xp + io.w);
        }
    };
    auto blendStore = [&](int buf) {
        #pragma unroll
        for (int i = 0; i < 2; ++i) {
            int p = (wv << 4) + (i << 3) + pg;
            uint4 o4;
            o4.x = blend2pk(c00[i].x, c01[i].x, c10[i].x, c11[i].x, cw[i]);
            o4.y = blend2pk(c00[i].y, c01[i].y, c10[i].y, c11[i].y, cw[i]);
            o4.z = blend2pk(c00[i].z, c01[i].z, c10[i].z, c11[i].z, cw[i]);
            o4.w = blend2pk(c00[i].w, c01[i].w, c10[i].w, c11[i].w, cw[i]);
            *(uint4*)&samp[buf][p][j8 << 3] = o4;
        }
    };

    // prologue: tap 0
    issue(0);
    afC[0] = *(const short8*)&wrow[0];
    afC[1] = *(const short8*)&wrow[32];
    blendStore(0);

    for (int k = 0; k < 9; ++k) {
        if (k < 8) {
            issue(k + 1);                           // VMEM in flight across barrier
            afN[0] = *(const short8*)&wrow[((k + 1) << 6)];
            afN[1] = *(const short8*)&wrow[((k + 1) << 6) + 32];
        }
        __syncthreads();                            // samp[k&1] complete block-wide
        #pragma unroll
        for (int ch = 0; ch < 2; ++ch) {
            #pragma unroll
            for (int nt = 0; nt < 4; ++nt) {
                short8 bfrag = *(const short8*)&samp[k & 1][(nt << 4) + r][(ch << 5) + (q << 3)];
                acc[nt] = __builtin_amdgcn_mfma_f32_16x16x32_bf16(afC[ch], bfrag, acc[nt], 0, 0, 0);
            }
        }
        if (k < 8) {
            blendStore((k + 1) & 1);
            afC[0] = afN[0];
            afC[1] = afN[1];
        }
    }

    #pragma unroll
    for (int nt = 0; nt < 4; ++nt) {
        #pragma unroll
        for (int reg = 0; reg < 4; ++reg) {
            int oc  = (wv << 4) + (q << 2) + reg;
            int pos = pos0 + (nt << 4) + r;
            float v = acc[nt][reg] + bias[oc];
            out[(size_t)(((b << 6) + oc) << 14) + pos] = fmaxf(v, 0.f);
        }
    }
}

// ---------------------------------------------------------------------------
extern "C" void kernel_launch(void* const* d_in, const int* in_sizes, int n_in,
                              void* d_out, int out_size, void* d_ws, size_t ws_size,
                              hipStream_t stream) {
    const float* data  = (const float*)d_in[0];
    const float* w     = (const float*)d_in[1];
    const float* bias  = (const float*)d_in[2];
    const float* w_off = (const float*)d_in[3];
    const float* b_off = (const float*)d_in[4];
    const float* w_mod = (const float*)d_in[5];
    const float* b_mod = (const float*)d_in[6];
    float* out = (float*)d_out;

    char* ws = (char*)d_ws;
    unsigned short* dataT   = (unsigned short*)(ws + OFF_DATAT);
    float*          offP    = (float*)(ws + OFF_OFFP);
    unsigned short* wpackM  = (unsigned short*)(ws + OFF_WM);
    unsigned short* wpack27 = (unsigned short*)(ws + OFF_W27);
    float*          bias27  = (float*)(ws + OFF_B27);

    pack_weights_k<<<216, 256, 0, stream>>>(w, w_off, w_mod, b_off, b_mod,
                                            wpackM, wpack27, bias27);
    transpose_k<<<2048, 256, 0, stream>>>(data, dataT);
    conv27_k<<<1024, 256, 0, stream>>>(dataT, wpack27, bias27, offP);
    deform_main_k<<<2048, 256, 0, stream>>>(dataT, wpackM, offP, bias, out);
}